// Round 3
// baseline (143.707 us; speedup 1.0000x reference)
//
#include <hip/hip_runtime.h>
#include <stdint.h>

// Problem constants
constexpr int ROWS = 64;
constexpr int D = 1 << 19;           // 524288 per row
constexpr uint32_t KSEL = 52428;     // int(0.1 * D)
constexpr int BPR = 16;              // blocks per row for scan passes
constexpr int CHUNK = D / BPR;       // 32768 elements per block
constexpr uint32_t CAND_MAX = 40960; // per-row candidate cap (mean ~33.3K, +43 sigma)
constexpr int LBUF = 4096;           // per-block candidate cap (mean ~2081, +45 sigma)
constexpr uint32_t B_LO = 0xBF9;     // predicted key-bucket range: floats [1.125, 1.5)
constexpr uint32_t B_HI = 0xBFB;     // threshold ~1.2816 +- 0.01 -> bucket 0xBFA, +-1 margin
constexpr uint32_t CNT_OVF = 0x40000000u;  // marker: block-local LBUF overflow

// Workspace layout (u32 indices)
constexpr size_t OFF_HIST = 0;                         // 64*4096
constexpr size_t OFF_CNT  = OFF_HIST + ROWS * 4096;    // 64
constexpr size_t OFF_CNT2 = OFF_CNT + 64;              // 64 (fallback)
constexpr size_t OFF_MISC = OFF_CNT2 + 64;             // [0]=any_fb; pad to 64
constexpr size_t ZERO_U32 = OFF_MISC + 64;             // zero everything above
constexpr size_t OFF_SEL  = ZERO_U32;                  // 64 (always rewritten)
constexpr size_t OFF_K2   = OFF_SEL + 64;              // 64
constexpr size_t OFF_FB   = OFF_K2 + 64;               // 64
constexpr size_t OFF_THR  = OFF_FB + 64;               // 64
constexpr size_t OFF_CAND = OFF_THR + 64;              // 64*CAND_MAX  (~10.5 MB)

// Monotonic key: larger float -> larger uint
__device__ __forceinline__ uint32_t mono(uint32_t f) {
    uint32_t m = (uint32_t)((int32_t)f >> 31) | 0x80000000u;
    return f ^ m;
}

__global__ __launch_bounds__(256) void zero_ws(uint32_t* __restrict__ ws) {
    const size_t n4 = ZERO_U32 / 4;  // 262336/4, exact
    uint4* p = (uint4*)ws;
    for (size_t i = (size_t)blockIdx.x * 256 + threadIdx.x; i < n4;
         i += (size_t)gridDim.x * 256)
        p[i] = make_uint4(0, 0, 0, 0);
}

// Fused pass: 12-bit histogram + compact keys in predicted bucket range.
__global__ __launch_bounds__(256) void hist_compact(const uint32_t* __restrict__ x,
                                                    uint32_t* __restrict__ ws) {
    __shared__ uint32_t lh[4096];
    __shared__ uint32_t lbuf[LBUF];
    __shared__ uint32_t ln, gbase;
    for (int i = threadIdx.x; i < 4096; i += 256) lh[i] = 0;
    if (threadIdx.x == 0) ln = 0;
    __syncthreads();
    int row = blockIdx.x / BPR, chunk = blockIdx.x % BPR;
    const uint4* p = (const uint4*)(x + (size_t)row * D + (size_t)chunk * CHUNK);
    for (int i = threadIdx.x; i < CHUNK / 4; i += 256) {
        uint4 v = p[i];
        uint32_t u;
#define PROC(c)                                                        \
        u = mono(c);                                                   \
        atomicAdd(&lh[u >> 20], 1u);                                   \
        if ((u >> 20) - B_LO <= (B_HI - B_LO)) {                       \
            uint32_t s = atomicAdd(&ln, 1u);                           \
            if (s < (uint32_t)LBUF) lbuf[s] = u;                       \
        }
        PROC(v.x) PROC(v.y) PROC(v.z) PROC(v.w)
#undef PROC
    }
    __syncthreads();
    uint32_t* h = ws + OFF_HIST + (size_t)row * 4096;
    for (int i = threadIdx.x; i < 4096; i += 256) {
        uint32_t c = lh[i];
        if (c) atomicAdd(&h[i], c);
    }
    uint32_t m = ln < (uint32_t)LBUF ? ln : (uint32_t)LBUF;
    if (threadIdx.x == 0) {
        uint32_t add = m + (ln > (uint32_t)LBUF ? CNT_OVF : 0u);
        gbase = atomicAdd(&ws[OFF_CNT + row], add);
    }
    __syncthreads();
    uint32_t base = gbase & (CNT_OVF - 1);
    uint32_t* cand = ws + OFF_CAND + (size_t)row * CAND_MAX;
    for (uint32_t i = threadIdx.x; i < m; i += 256) {
        uint32_t slot = base + i;
        if (slot < CAND_MAX) cand[slot] = lbuf[i];
    }
}

// Per-row select over 4096 bins (descending): exact bucket of K-th largest,
// in-bucket rank, count above predicted range, fallback decision.
__global__ __launch_bounds__(256) void select1(uint32_t* __restrict__ ws) {
    constexpr int PER = 16;
    __shared__ uint32_t sc[256];
    __shared__ uint32_t sa[256];
    __shared__ uint32_t bcast[2];
    int row = blockIdx.x, t = threadIdx.x;
    const uint32_t* h = ws + OFF_HIST + (size_t)row * 4096;
    int hi = 4095 - t * PER;
    uint32_t s = 0, above = 0;
    for (int j = 0; j < PER; ++j) {
        uint32_t c = h[hi - j];
        s += c;
        if ((uint32_t)(hi - j) > B_HI) above += c;
    }
    sc[t] = s; sa[t] = above;
    __syncthreads();
    for (int off = 1; off < 256; off <<= 1) {
        uint32_t v = (t >= off) ? sc[t - off] : 0u;
        __syncthreads();
        sc[t] += v;
        __syncthreads();
    }
    // reduce 'above'
    for (int off = 128; off > 0; off >>= 1) {
        if (t < off) sa[t] += sa[t + off];
        __syncthreads();
    }
    uint32_t excl = sc[t] - s;
    if (excl < KSEL && excl + s >= KSEL) {
        uint32_t c = excl;
        for (int j = 0; j < PER; ++j) {
            int bin = hi - j;
            uint32_t hb = h[bin];
            c += hb;
            if (c >= KSEL) {
                bcast[0] = (uint32_t)bin;
                bcast[1] = KSEL - (c - hb);  // in-bucket rank (1-based)
                break;
            }
        }
    }
    __syncthreads();
    if (t == 0) {
        uint32_t sb = bcast[0], r = bcast[1];
        uint32_t cnt = ws[OFF_CNT + row];
        bool fb = (sb < B_LO) || (sb > B_HI) || (cnt > CAND_MAX);
        ws[OFF_SEL + row] = sb;
        ws[OFF_FB + row] = fb ? 1u : 0u;
        ws[OFF_K2 + row] = fb ? r : (KSEL - sa[0]);  // rank among candidates
        if (fb) ws[OFF_MISC] = 1u;
    }
}

// Fallback compact (normally a no-op): gather keys in the exact selected
// bucket for rows flagged fb. Direct global atomics (rare path).
__global__ __launch_bounds__(256) void fallback_compact(const uint32_t* __restrict__ x,
                                                        uint32_t* __restrict__ ws) {
    if (ws[OFF_MISC] == 0u) return;
    int row = blockIdx.x / BPR, chunk = blockIdx.x % BPR;
    if (ws[OFF_FB + row] == 0u) return;
    uint32_t sb = ws[OFF_SEL + row];
    uint32_t* cand = ws + OFF_CAND + (size_t)row * CAND_MAX;
    const uint4* p = (const uint4*)(x + (size_t)row * D + (size_t)chunk * CHUNK);
    for (int i = threadIdx.x; i < CHUNK / 4; i += 256) {
        uint4 v = p[i];
        uint32_t u;
#define PROC(c)                                                        \
        u = mono(c);                                                   \
        if ((u >> 20) == sb) {                                         \
            uint32_t s = atomicAdd(&ws[OFF_CNT2 + row], 1u);           \
            if (s < CAND_MAX) cand[s] = u;                             \
        }
        PROC(v.x) PROC(v.y) PROC(v.z) PROC(v.w)
#undef PROC
    }
}

// One block per row: exact select of k2-th largest among candidates via two
// 11-bit LDS radix levels over the low 22 bits (top 10 bits shared).
__global__ __launch_bounds__(256) void final_select(uint32_t* __restrict__ ws) {
    __shared__ uint32_t h[2048];
    __shared__ uint32_t sc[256];
    __shared__ uint32_t bcast[2];
    int row = blockIdx.x, t = threadIdx.x;
    uint32_t fb = ws[OFF_FB + row];
    uint32_t n = fb ? ws[OFF_CNT2 + row] : ws[OFF_CNT + row];
    if (n > CAND_MAX) n = CAND_MAX;
    const uint32_t* c = ws + OFF_CAND + (size_t)row * CAND_MAX;
    uint32_t k = ws[OFF_K2 + row];
    uint32_t sb = ws[OFF_SEL + row];

    // Level 1: bits 21..11
    for (int i = t; i < 2048; i += 256) h[i] = 0;
    __syncthreads();
    for (uint32_t i = t; i < n; i += 256) atomicAdd(&h[(c[i] >> 11) & 0x7FFu], 1u);
    __syncthreads();
    {
        int hi = 2047 - t * 8;
        uint32_t s = 0;
        for (int j = 0; j < 8; ++j) s += h[hi - j];
        sc[t] = s;
        __syncthreads();
        for (int off = 1; off < 256; off <<= 1) {
            uint32_t v = (t >= off) ? sc[t - off] : 0u;
            __syncthreads();
            sc[t] += v;
            __syncthreads();
        }
        uint32_t excl = sc[t] - s;
        if (excl < k && excl + s >= k) {
            uint32_t cc = excl;
            for (int j = 0; j < 8; ++j) {
                int bin = hi - j;
                uint32_t hb = h[bin];
                cc += hb;
                if (cc >= k) { bcast[0] = (uint32_t)bin; bcast[1] = k - (cc - hb); break; }
            }
        }
    }
    __syncthreads();
    uint32_t b1 = bcast[0], k2 = bcast[1];
    __syncthreads();

    // Level 2: bits 10..0 among candidates matching b1
    for (int i = t; i < 2048; i += 256) h[i] = 0;
    __syncthreads();
    for (uint32_t i = t; i < n; i += 256) {
        uint32_t u = c[i];
        if (((u >> 11) & 0x7FFu) == b1) atomicAdd(&h[u & 0x7FFu], 1u);
    }
    __syncthreads();
    {
        int hi = 2047 - t * 8;
        uint32_t s = 0;
        for (int j = 0; j < 8; ++j) s += h[hi - j];
        sc[t] = s;
        __syncthreads();
        for (int off = 1; off < 256; off <<= 1) {
            uint32_t v = (t >= off) ? sc[t - off] : 0u;
            __syncthreads();
            sc[t] += v;
            __syncthreads();
        }
        uint32_t excl = sc[t] - s;
        if (excl < k2 && excl + s >= k2) {
            uint32_t cc = excl;
            for (int j = 0; j < 8; ++j) {
                int bin = hi - j;
                uint32_t hb = h[bin];
                cc += hb;
                if (cc >= k2) {
                    uint32_t u = ((sb >> 2) << 22) | (b1 << 11) | (uint32_t)bin;
                    uint32_t m = (u & 0x80000000u) ? 0x80000000u : 0xFFFFFFFFu;
                    ws[OFF_THR + row] = u ^ m;  // float bits of exact K-th largest
                    break;
                }
            }
        }
    }
}

// Final mask: out = (x < thr) ? x : 0, float4-vectorized.
__global__ __launch_bounds__(256) void mask_pass(const float4* __restrict__ x,
                                                 float4* __restrict__ out,
                                                 const uint32_t* __restrict__ thr_bits) {
    const int64_t total4 = (int64_t)ROWS * (D / 4);
    for (int64_t i = (int64_t)blockIdx.x * 256 + threadIdx.x; i < total4;
         i += (int64_t)gridDim.x * 256) {
        int row = (int)(i >> 17);  // D/4 = 2^17 float4 per row
        float tv = __uint_as_float(thr_bits[row]);
        float4 v = x[i];
        v.x = (v.x < tv) ? v.x : 0.0f;
        v.y = (v.y < tv) ? v.y : 0.0f;
        v.z = (v.z < tv) ? v.z : 0.0f;
        v.w = (v.w < tv) ? v.w : 0.0f;
        out[i] = v;
    }
}

extern "C" void kernel_launch(void* const* d_in, const int* in_sizes, int n_in,
                              void* d_out, int out_size, void* d_ws, size_t ws_size,
                              hipStream_t stream) {
    (void)in_sizes; (void)n_in; (void)out_size; (void)ws_size;
    const uint32_t* xu = (const uint32_t*)d_in[0];
    uint32_t* ws = (uint32_t*)d_ws;

    zero_ws<<<64, 256, 0, stream>>>(ws);
    hist_compact<<<ROWS * BPR, 256, 0, stream>>>(xu, ws);
    select1<<<ROWS, 256, 0, stream>>>(ws);
    fallback_compact<<<ROWS * BPR, 256, 0, stream>>>(xu, ws);
    final_select<<<ROWS, 256, 0, stream>>>(ws);
    mask_pass<<<4096, 256, 0, stream>>>((const float4*)d_in[0], (float4*)d_out,
                                        ws + OFF_THR);
}